// Round 5
// baseline (517.169 us; speedup 1.0000x reference)
//
#include <hip/hip_runtime.h>

typedef unsigned int uint;
typedef unsigned short ushort;
typedef _Float16 h2 __attribute__((ext_vector_type(2)));
typedef _Float16 f16x8 __attribute__((ext_vector_type(8)));
typedef float f32x4 __attribute__((ext_vector_type(4)));

#define HW 65536
#define W_ 256
#define H_ 256
#define C_ 64

__device__ __forceinline__ ushort f2hu(float f) { union { ushort u; _Float16 h; } x; x.h = (_Float16)f; return x.u; }
__device__ __forceinline__ float hu2f(ushort u) { union { ushort u; _Float16 h; } x; x.u = u; return (float)x.h; }
__device__ __forceinline__ h2 u2h2(uint u) { union { uint u; h2 h; } x; x.u = u; return x.h; }
__device__ __forceinline__ uint h22u(h2 h) { union { uint u; h2 h; } x; x.h = h; return x.u; }

#define MFMA16(a, b, c) __builtin_amdgcn_mfma_f32_16x16x32_f16((a), (b), (c), 0, 0, 0)

// ---------------- convert 6 weight matrices (4096 fp32 each) to f16, same [o][c] layout ----------------
__global__ __launch_bounds__(256) void wconv_k(const float* __restrict__ a0, const float* __restrict__ a1,
                                               const float* __restrict__ a2, const float* __restrict__ a3,
                                               const float* __restrict__ a4, const float* __restrict__ a5,
                                               ushort* __restrict__ dst) {
    int m = blockIdx.x;
    const float* src = m == 0 ? a0 : m == 1 ? a1 : m == 2 ? a2 : m == 3 ? a3 : m == 4 ? a4 : a5;
    ushort* d = dst + m * 4096;
    for (int i = threadIdx.x; i < 4096; i += 256) d[i] = f2hu(src[i]);
}

// ---------------- pack pa_w (64*98 fp32) into duplicated-h2 uints ----------------
__global__ __launch_bounds__(128) void wpk_k(const float* __restrict__ pw, uint* __restrict__ dst) {
    for (int i = threadIdx.x + blockIdx.x * 128; i < 6272; i += gridDim.x * 128) {
        ushort hv = f2hu(pw[i]);
        dst[i] = (uint)hv | ((uint)hv << 16);
    }
}

// ---------------- conv1x1 via MFMA: y[b,o,hw] = W[o,c] x[b,c,hw] + bias[o], f16 NCHW out ----------------
__global__ __launch_bounds__(256, 2) void c1_k(const float* __restrict__ x,
                                               const ushort* __restrict__ wf,
                                               const float* __restrict__ bias,
                                               ushort* __restrict__ y) {
    __shared__ ushort sY[64 * 264];     // [o][pix], stride 264
    int tid = threadIdx.x;
    int wv = tid >> 6, lane = tid & 63;
    int l15 = lane & 15, quad = lane >> 4;
    int pix0 = blockIdx.x * 256;
    int b = pix0 >> 16, hw0 = pix0 & 65535;
    const float* xb = x + ((size_t)b << 22) + hw0;

    f16x8 aX[4][2];
#pragma unroll
    for (int mt = 0; mt < 4; ++mt) {
        int pixl = wv * 64 + mt * 16 + l15;
#pragma unroll
        for (int kc = 0; kc < 2; ++kc) {
            f16x8 a;
#pragma unroll
            for (int j = 0; j < 8; ++j) {
                int c = kc * 32 + quad * 8 + j;
                a[j] = (_Float16)xb[((size_t)c << 16) + pixl];
            }
            aX[mt][kc] = a;
        }
    }
    f16x8 bW[4][2];
#pragma unroll
    for (int nt = 0; nt < 4; ++nt)
#pragma unroll
        for (int kc = 0; kc < 2; ++kc)
            bW[nt][kc] = *(const f16x8*)(wf + (nt * 16 + l15) * 64 + kc * 32 + quad * 8);

    f32x4 acc[4][4];
#pragma unroll
    for (int mt = 0; mt < 4; ++mt)
#pragma unroll
        for (int nt = 0; nt < 4; ++nt) {
            f32x4 s = (f32x4)(0.0f);
            s = MFMA16(aX[mt][0], bW[nt][0], s);
            s = MFMA16(aX[mt][1], bW[nt][1], s);
            acc[mt][nt] = s;
        }

#pragma unroll
    for (int nt = 0; nt < 4; ++nt) {
        int o = nt * 16 + l15;
        float bv = bias[o];
#pragma unroll
        for (int mt = 0; mt < 4; ++mt) {
            int pixl = wv * 64 + mt * 16 + quad * 4;
#pragma unroll
            for (int r = 0; r < 4; r += 2) {
                h2 hh;
                hh.x = (_Float16)(acc[mt][nt][r] + bv);
                hh.y = (_Float16)(acc[mt][nt][r + 1] + bv);
                *(h2*)&sY[o * 264 + pixl + r] = hh;
            }
        }
    }
    __syncthreads();
    ushort* yb = y + ((size_t)b << 22) + hw0;
#pragma unroll
    for (int i = 0; i < 16; ++i) {
        int o = wv * 16 + i;
        uint2 v = *(const uint2*)&sY[o * 264 + lane * 4];
        *(uint2*)(yb + ((size_t)o << 16) + lane * 4) = v;
    }
}

// ------- depthwise 3x3 (zero pad) + bias, NCHW f16 in -> f16 out -------
// mode==0: out[bh*16384 + w*64 + c]   (channels-last, for Q)
// mode==2: out[bh*16384 + c*256 + w]  (plane layout, for V)
__global__ __launch_bounds__(256) void dw3x3_t_k(const ushort* __restrict__ x,
                                                 const float* __restrict__ wgt,
                                                 const float* __restrict__ bias,
                                                 ushort* __restrict__ out,
                                                 int mode) {
    int wt = blockIdx.x;   // 0..3 (w tile of 64)
    int h  = blockIdx.y;   // 0..255
    int b  = blockIdx.z;   // 0..1
    int tid = threadIdx.x;
    int wl = tid & 63, cg = tid >> 6;
    int w0 = wt * 64;
    __shared__ float tile[64][65];   // [w][c]

    // clamped offsets + masks (branch-free tap loads)
    int hcl[3]; float mrow[3];
#pragma unroll
    for (int dy = 0; dy < 3; ++dy) {
        int hh = h + dy - 1;
        mrow[dy] = (hh >= 0 && hh < H_) ? 1.0f : 0.0f;
        hcl[dy] = hh < 0 ? 0 : (hh > 255 ? 255 : hh);
    }
    int wcl[3]; float m9[9];
#pragma unroll
    for (int dx = 0; dx < 3; ++dx) {
        int ww = w0 + wl + dx - 1;
        float mc = (ww >= 0 && ww < W_) ? 1.0f : 0.0f;
        wcl[dx] = ww < 0 ? 0 : (ww > 255 ? 255 : ww);
#pragma unroll
        for (int dy = 0; dy < 3; ++dy) m9[dy * 3 + dx] = mrow[dy] * mc;
    }

#pragma unroll 4
    for (int i = 0; i < 16; ++i) {
        int c = i * 4 + cg;                       // wave-uniform
        const float* wp = wgt + c * 9;
        float acc = bias[c];
        const ushort* xp = x + (((size_t)b * 64 + c) << 16);
#pragma unroll
        for (int t = 0; t < 9; ++t) {
            float v = hu2f(xp[hcl[t / 3] * W_ + wcl[t % 3]]);
            acc = fmaf(wp[t] * m9[t], v, acc);
        }
        tile[wl][c] = acc;
    }
    __syncthreads();
    size_t bh16 = ((size_t)b * H_ + h) * (size_t)(W_ * 64);
    if (mode == 0) {
        uint4* og = (uint4*)(out + bh16 + (size_t)w0 * 64);
#pragma unroll
        for (int u = 0; u < 2; ++u) {
            int i0 = (u * 256 + tid) * 8;
            ushort vals[8];
#pragma unroll
            for (int k = 0; k < 8; ++k) {
                int i = i0 + k;
                vals[k] = f2hu(tile[i >> 6][i & 63]);
            }
            uint4 o;
            o.x = (uint)vals[0] | ((uint)vals[1] << 16);
            o.y = (uint)vals[2] | ((uint)vals[3] << 16);
            o.z = (uint)vals[4] | ((uint)vals[5] << 16);
            o.w = (uint)vals[6] | ((uint)vals[7] << 16);
            og[u * 256 + tid] = o;
        }
    } else {
#pragma unroll
        for (int u = 0; u < 2; ++u) {
            int i = u * 256 + tid;           // 0..511 uint4 index
            int c = i >> 3, wch = i & 7;
            ushort vals[8];
#pragma unroll
            for (int k = 0; k < 8; ++k) vals[k] = f2hu(tile[wch * 8 + k][c]);
            uint4 o;
            o.x = (uint)vals[0] | ((uint)vals[1] << 16);
            o.y = (uint)vals[2] | ((uint)vals[3] << 16);
            o.z = (uint)vals[4] | ((uint)vals[5] << 16);
            o.w = (uint)vals[6] | ((uint)vals[7] << 16);
            *(uint4*)(out + bh16 + (size_t)c * 256 + w0 + wch * 8) = o;
        }
    }
}

// ---------------- combined MFMA attention (unchanged, verified) ----------------
__global__ __launch_bounds__(256, 2) void att2_k(const ushort* __restrict__ Ql,
                                                 const ushort* __restrict__ Qr,
                                                 const ushort* __restrict__ Vl,
                                                 const ushort* __restrict__ Vr,
                                                 ushort* __restrict__ Fr2l,
                                                 ushort* __restrict__ Fl2r) {
    int bh = blockIdx.x;
    int tid = threadIdx.x;
    int wv = tid >> 6, lane = tid & 63;
    int l15 = lane & 15, quad = lane >> 4;
    __shared__ ushort sE[256 * 72];    // E row-major [p][kcol], stride 72
    __shared__ ushort sEt[64 * 264];   // E col-major [kcol][p], stride 264

    const ushort* qlb = Ql + (size_t)bh * 16384;
    const ushort* qrb = Qr + (size_t)bh * 16384;
    const ushort* vlb = Vl + (size_t)bh * 16384;
    const ushort* vrb = Vr + (size_t)bh * 16384;
    int p0 = wv * 64;
    int c0 = wv * 16;

    f16x8 aQ[4][2];
#pragma unroll
    for (int mt = 0; mt < 4; ++mt)
#pragma unroll
        for (int kc = 0; kc < 2; ++kc)
            aQ[mt][kc] = *(const f16x8*)(qlb + (p0 + mt * 16 + l15) * 64 + kc * 32 + quad * 8);

    f16x8 onesf;
#pragma unroll
    for (int i = 0; i < 8; ++i) onesf[i] = (_Float16)1.0f;

    f32x4 num1[4][4];
    f32x4 den[4];
#pragma unroll
    for (int mt = 0; mt < 4; ++mt) {
        den[mt] = (f32x4)(0.0f);
#pragma unroll
        for (int nt = 0; nt < 4; ++nt) num1[mt][nt] = (f32x4)(0.0f);
    }

    for (int kt = 0; kt < 4; ++kt) {
        int k0 = kt * 64;
        f32x4 S[4][4];
#pragma unroll
        for (int nt = 0; nt < 4; ++nt) {
            f16x8 bQ[2];
#pragma unroll
            for (int kc = 0; kc < 2; ++kc)
                bQ[kc] = *(const f16x8*)(qrb + (k0 + nt * 16 + l15) * 64 + kc * 32 + quad * 8);
#pragma unroll
            for (int mt = 0; mt < 4; ++mt) {
                f32x4 s = (f32x4)(0.0f);
                s = MFMA16(aQ[mt][0], bQ[0], s);
                s = MFMA16(aQ[mt][1], bQ[1], s);
                S[mt][nt] = s;
            }
        }
#pragma unroll
        for (int mt = 0; mt < 4; ++mt)
#pragma unroll
            for (int nt = 0; nt < 4; ++nt)
#pragma unroll
                for (int r = 0; r < 4; ++r)
                    S[mt][nt][r] = __expf(S[mt][nt][r] * 0.125f);

        __syncthreads();
#pragma unroll
        for (int mt = 0; mt < 4; ++mt)
#pragma unroll
            for (int nt = 0; nt < 4; ++nt)
#pragma unroll
                for (int r = 0; r < 4; ++r)
                    sE[(p0 + mt * 16 + quad * 4 + r) * 72 + nt * 16 + l15] = f2hu(S[mt][nt][r]);
#pragma unroll
        for (int mt = 0; mt < 4; ++mt)
#pragma unroll
            for (int nt = 0; nt < 4; ++nt)
#pragma unroll
            for (int pr = 0; pr < 4; pr += 2) {
                h2 hh;
                hh.x = (_Float16)S[mt][nt][pr];
                hh.y = (_Float16)S[mt][nt][pr + 1];
                *(h2*)&sEt[(nt * 16 + l15) * 264 + p0 + mt * 16 + quad * 4 + pr] = hh;
            }
        __syncthreads();

        f16x8 aE[4][2];
#pragma unroll
        for (int mt = 0; mt < 4; ++mt)
#pragma unroll
            for (int kc = 0; kc < 2; ++kc)
                aE[mt][kc] = *(const f16x8*)&sE[(p0 + mt * 16 + l15) * 72 + kc * 32 + quad * 8];
#pragma unroll
        for (int mt = 0; mt < 4; ++mt) {
            den[mt] = MFMA16(aE[mt][0], onesf, den[mt]);
            den[mt] = MFMA16(aE[mt][1], onesf, den[mt]);
        }
#pragma unroll
        for (int nt = 0; nt < 4; ++nt) {
            f16x8 bV[2];
#pragma unroll
            for (int kc = 0; kc < 2; ++kc)
                bV[kc] = *(const f16x8*)(vrb + (nt * 16 + l15) * 256 + k0 + kc * 32 + quad * 8);
#pragma unroll
            for (int mt = 0; mt < 4; ++mt) {
                num1[mt][nt] = MFMA16(aE[mt][0], bV[0], num1[mt][nt]);
                num1[mt][nt] = MFMA16(aE[mt][1], bV[1], num1[mt][nt]);
            }
        }
        f32x4 num2[4], den2[4];
#pragma unroll
        for (int mt = 0; mt < 4; ++mt) { num2[mt] = (f32x4)(0.0f); den2[mt] = (f32x4)(0.0f); }
        for (int pc = 0; pc < 8; ++pc) {
            f16x8 bL = *(const f16x8*)(vlb + (c0 + l15) * 256 + pc * 32 + quad * 8);
#pragma unroll
            for (int mt = 0; mt < 4; ++mt) {
                f16x8 aT = *(const f16x8*)&sEt[(mt * 16 + l15) * 264 + pc * 32 + quad * 8];
                num2[mt] = MFMA16(aT, bL, num2[mt]);
                den2[mt] = MFMA16(aT, onesf, den2[mt]);
            }
        }
#pragma unroll
        for (int mt = 0; mt < 4; ++mt)
#pragma unroll
            for (int r = 0; r < 4; ++r) {
                float v = num2[mt][r] * (1.0f / den2[mt][r]);
                Fl2r[(size_t)bh * 16384 + (k0 + mt * 16 + quad * 4 + r) * 64 + c0 + l15] = f2hu(v);
            }
    }
#pragma unroll
    for (int mt = 0; mt < 4; ++mt)
#pragma unroll
        for (int r = 0; r < 4; ++r) {
            float inv = 1.0f / den[mt][r];
#pragma unroll
            for (int nt = 0; nt < 4; ++nt) {
                float v = num1[mt][nt][r] * inv;
                Fr2l[(size_t)bh * 16384 + (p0 + mt * 16 + quad * 4 + r) * 64 + nt * 16 + l15] = f2hu(v);
            }
        }
}

// ------- pattn1 = lp3(F_r2l) + rp3(F_l2r) via MFMA; channels-last f16 in, NCHW f16 out -------
__global__ __launch_bounds__(256, 2) void p3m_k(const ushort* __restrict__ F1,
                                                const ushort* __restrict__ F2,
                                                const ushort* __restrict__ wf1,
                                                const float* __restrict__ b1,
                                                const ushort* __restrict__ wf2,
                                                const float* __restrict__ b2,
                                                ushort* __restrict__ outp) {
    __shared__ ushort sY[64 * 264];
    int tid = threadIdx.x;
    int wv = tid >> 6, lane = tid & 63;
    int l15 = lane & 15, quad = lane >> 4;
    int pix0 = blockIdx.x * 256;
    int b = pix0 >> 16, hw0 = pix0 & 65535;

    f32x4 acc[4][4];
#pragma unroll
    for (int mt = 0; mt < 4; ++mt)
#pragma unroll
        for (int nt = 0; nt < 4; ++nt) acc[mt][nt] = (f32x4)(0.0f);

    for (int mat = 0; mat < 2; ++mat) {
        const ushort* F = mat == 0 ? F1 : F2;
        const ushort* wf = mat == 0 ? wf1 : wf2;
        f16x8 aF[4][2], bW[4][2];
#pragma unroll
        for (int mt = 0; mt < 4; ++mt) {
            int pixg = pix0 + wv * 64 + mt * 16 + l15;
#pragma unroll
            for (int kc = 0; kc < 2; ++kc)
                aF[mt][kc] = *(const f16x8*)(F + (size_t)pixg * 64 + kc * 32 + quad * 8);
        }
#pragma unroll
        for (int nt = 0; nt < 4; ++nt)
#pragma unroll
            for (int kc = 0; kc < 2; ++kc)
                bW[nt][kc] = *(const f16x8*)(wf + (nt * 16 + l15) * 64 + kc * 32 + quad * 8);
#pragma unroll
        for (int mt = 0; mt < 4; ++mt)
#pragma unroll
            for (int nt = 0; nt < 4; ++nt) {
                acc[mt][nt] = MFMA16(aF[mt][0], bW[nt][0], acc[mt][nt]);
                acc[mt][nt] = MFMA16(aF[mt][1], bW[nt][1], acc[mt][nt]);
            }
    }

#pragma unroll
    for (int nt = 0; nt < 4; ++nt) {
        int o = nt * 16 + l15;
        float bv = b1[o] + b2[o];
#pragma unroll
        for (int mt = 0; mt < 4; ++mt) {
            int pixl = wv * 64 + mt * 16 + quad * 4;
#pragma unroll
            for (int r = 0; r < 4; r += 2) {
                h2 hh;
                hh.x = (_Float16)(acc[mt][nt][r] + bv);
                hh.y = (_Float16)(acc[mt][nt][r + 1] + bv);
                *(h2*)&sY[o * 264 + pixl + r] = hh;
            }
        }
    }
    __syncthreads();
    ushort* yb = outp + ((size_t)b << 22) + hw0;
#pragma unroll
    for (int i = 0; i < 16; ++i) {
        int o = wv * 16 + i;
        uint2 v = *(const uint2*)&sY[o * 264 + lane * 4];
        *(uint2*)(yb + ((size_t)o << 16) + lane * 4) = v;
    }
}

// ------- pixel attention 7x7 reflect + double sigmoid + blend; packed-h2, LDS-tiled -------
// block = 128 threads, one (b,c,16-row) tile; lane owns output cols (w, w+128) packed in h2.
// s2a[e] = (s[e-3], s[e-3+128]) per staged row; x_r reconstructed as s - x_l.
__global__ __launch_bounds__(128) void p4pk_k(const float* __restrict__ x_l,
                                              const float* __restrict__ x_r,
                                              const ushort* __restrict__ pt,
                                              const uint* __restrict__ pw2,
                                              const float* __restrict__ pb,
                                              float* __restrict__ out) {
    __shared__ uint s2a[22 * 136];
    __shared__ uint p2a[22 * 136];
    __shared__ uint xl2[16 * 128];
    int tid = threadIdx.x;           // 0..127
    int tile = blockIdx.x & 15;
    int bc = blockIdx.x >> 4;        // b*64 + c
    int c = bc & 63;
    int h0 = tile << 4;
    size_t cbase = (size_t)bc << 16;

#pragma unroll
    for (int r = 0; r < 22; ++r) {
        int hh = h0 + r - 3;
        hh = hh < 0 ? -hh : (hh > 255 ? 510 - hh : hh);
        size_t rb = cbase + (size_t)hh * 256;
        int k1 = tid - 3;
        int s1 = k1 < 0 ? -k1 : k1;          // left reflect
        int k2 = tid + 125;                  // always <= 252, in range
        float a1 = x_l[rb + s1] + x_r[rb + s1];
        float a2 = x_l[rb + k2] + x_r[rb + k2];
        s2a[r * 136 + tid] = (uint)f2hu(a1) | ((uint)f2hu(a2) << 16);
        p2a[r * 136 + tid] = (uint)pt[rb + s1] | ((uint)pt[rb + k2] << 16);
        if (tid < 6) {                       // entries e = 128..133
            int e = 128 + tid;
            int k1b = e - 3;                 // 125..130, in range
            int k2b = e + 125;               // 253..258
            int s2b = k2b > 255 ? 510 - k2b : k2b;
            float b1v = x_l[rb + k1b] + x_r[rb + k1b];
            float b2v = x_l[rb + s2b] + x_r[rb + s2b];
            s2a[r * 136 + e] = (uint)f2hu(b1v) | ((uint)f2hu(b2v) << 16);
            p2a[r * 136 + e] = (uint)pt[rb + k1b] | ((uint)pt[rb + s2b] << 16);
        }
        if (r >= 3 && r < 19) {              // stash x_l rows h0..h0+15 (never reflected)
            xl2[(r - 3) * 128 + tid] = (uint)f2hu(x_l[rb + tid]) | ((uint)f2hu(x_l[rb + tid + 128]) << 16);
        }
    }
    __syncthreads();

    const uint* wA = pw2 + c * 98;       // duplicated-h2 weights vs s
    const uint* wB = wA + 49;            // vs pattn1
    float bv = pb[c];
    h2 bias2; bias2.x = (_Float16)bv; bias2.y = (_Float16)bv;
    h2 a0 = bias2, a1 = bias2, a2 = bias2, a3 = bias2, a4 = bias2, a5 = bias2, a6 = bias2;

#pragma unroll
    for (int r = 0; r < 22; ++r) {
#pragma unroll
        for (int j = 0; j < 7; ++j) {
            h2 sv = u2h2(s2a[r * 136 + tid + j]);
            h2 pv = u2h2(p2a[r * 136 + tid + j]);
            a0 += u2h2(wA[42 + j]) * sv + u2h2(wB[42 + j]) * pv;
            a1 += u2h2(wA[35 + j]) * sv + u2h2(wB[35 + j]) * pv;
            a2 += u2h2(wA[28 + j]) * sv + u2h2(wB[28 + j]) * pv;
            a3 += u2h2(wA[21 + j]) * sv + u2h2(wB[21 + j]) * pv;
            a4 += u2h2(wA[14 + j]) * sv + u2h2(wB[14 + j]) * pv;
            a5 += u2h2(wA[ 7 + j]) * sv + u2h2(wB[ 7 + j]) * pv;
            a6 += u2h2(wA[     j]) * sv + u2h2(wB[     j]) * pv;
        }
        if (r >= 6) {
            int o = r - 6;
            h2 sc = u2h2(s2a[(o + 3) * 136 + tid + 3]);   // s at (h0+o, w) / (w+128)
            h2 xv = u2h2(xl2[o * 128 + tid]);             // x_l at same
            float accx = (float)a0.x, accy = (float)a0.y;
            float s1x = 1.0f / (1.0f + __expf(-accx));
            float s1y = 1.0f / (1.0f + __expf(-accy));
            float ax = 1.0f / (1.0f + __expf(-s1x));
            float ay = 1.0f / (1.0f + __expf(-s1y));
            float xlx = (float)xv.x, xly = (float)xv.y;
            float xrx = (float)sc.x - xlx, xry = (float)sc.y - xly;
            size_t idx = cbase + (size_t)(h0 + o) * 256 + tid;
            out[idx] = xrx + ax * (xlx - xrx);
            out[idx + 128] = xry + ay * (xly - xry);
        }
        a0 = a1; a1 = a2; a2 = a3; a3 = a4; a4 = a5; a5 = a6; a6 = bias2;
    }
}

extern "C" void kernel_launch(void* const* d_in, const int* in_sizes, int n_in,
                              void* d_out, int out_size, void* d_ws, size_t ws_size,
                              hipStream_t stream) {
    const float* x_l = (const float*)d_in[0];
    const float* x_r = (const float*)d_in[1];
    const float* lp1_w1 = (const float*)d_in[2];
    const float* lp1_b1 = (const float*)d_in[3];
    const float* lp1_w2 = (const float*)d_in[4];
    const float* lp1_b2 = (const float*)d_in[5];
    const float* rp1_w1 = (const float*)d_in[6];
    const float* rp1_b1 = (const float*)d_in[7];
    const float* rp1_w2 = (const float*)d_in[8];
    const float* rp1_b2 = (const float*)d_in[9];
    const float* lp2_w1 = (const float*)d_in[10];
    const float* lp2_b1 = (const float*)d_in[11];
    const float* lp2_w2 = (const float*)d_in[12];
    const float* lp2_b2 = (const float*)d_in[13];
    const float* rp2_w1 = (const float*)d_in[14];
    const float* rp2_b1 = (const float*)d_in[15];
    const float* rp2_w2 = (const float*)d_in[16];
    const float* rp2_b2 = (const float*)d_in[17];
    const float* lp3_w = (const float*)d_in[18];
    const float* lp3_b = (const float*)d_in[19];
    const float* rp3_w = (const float*)d_in[20];
    const float* rp3_b = (const float*)d_in[21];
    const float* pa_w = (const float*)d_in[22];
    const float* pa_b = (const float*)d_in[23];

    const size_t N = (size_t)2 * 64 * 256 * 256;    // 8388608
    char* ws = (char*)d_ws;
    ushort* tmp  = (ushort*)ws;                     // N u16 (conv1x1 out, later pattn1)
    ushort* wf16 = (ushort*)(ws + N * 2);           // 6 * 4096 f16 weights [o][c]
    uint*   wp2  = (uint*)(ws + N * 2 + 65536);     // 6272 packed-h2 pa weights
    ushort* q_l   = (ushort*)(ws + N * 4);
    ushort* q_r   = q_l + N;
    ushort* v_l   = q_r + N;                        // plane layout
    ushort* v_r   = v_l + N;                        // plane layout
    ushort* f_r2l = v_r + N;
    ushort* f_l2r = f_r2l + N;

    dim3 blk(256);
    dim3 g_c1(512);            // B*HW/256
    dim3 g_dw(4, 256, 2);      // wtile, h, b
    dim3 g_att(512);           // b*h
    dim3 g_p3(512);            // B*HW/256
    dim3 g_p4(2048);           // (b*64+c)*16 + htile

    wconv_k<<<6, blk, 0, stream>>>(lp1_w1, rp1_w1, lp2_w1, rp2_w1, lp3_w, rp3_w, wf16);
    wpk_k<<<8, dim3(128), 0, stream>>>(pa_w, wp2);

    c1_k<<<g_c1, blk, 0, stream>>>(x_l, wf16 + 0 * 4096, lp1_b1, tmp);
    dw3x3_t_k<<<g_dw, blk, 0, stream>>>(tmp, lp1_w2, lp1_b2, q_l, 0);
    c1_k<<<g_c1, blk, 0, stream>>>(x_r, wf16 + 1 * 4096, rp1_b1, tmp);
    dw3x3_t_k<<<g_dw, blk, 0, stream>>>(tmp, rp1_w2, rp1_b2, q_r, 0);
    c1_k<<<g_c1, blk, 0, stream>>>(x_l, wf16 + 2 * 4096, lp2_b1, tmp);
    dw3x3_t_k<<<g_dw, blk, 0, stream>>>(tmp, lp2_w2, lp2_b2, v_l, 2);
    c1_k<<<g_c1, blk, 0, stream>>>(x_r, wf16 + 3 * 4096, rp2_b1, tmp);
    dw3x3_t_k<<<g_dw, blk, 0, stream>>>(tmp, rp2_w2, rp2_b2, v_r, 2);

    att2_k<<<g_att, blk, 0, stream>>>(q_l, q_r, v_l, v_r, f_r2l, f_l2r);

    p3m_k<<<g_p3, blk, 0, stream>>>(f_r2l, f_l2r, wf16 + 4 * 4096, lp3_b, wf16 + 5 * 4096, rp3_b, tmp);

    p4pk_k<<<g_p4, dim3(128), 0, stream>>>(x_l, x_r, tmp, wp2, pa_b, (float*)d_out);
}

// Round 6
// 516.973 us; speedup vs baseline: 1.0004x; 1.0004x over previous
//
#include <hip/hip_runtime.h>

typedef unsigned int uint;
typedef unsigned short ushort;
typedef _Float16 h2 __attribute__((ext_vector_type(2)));
typedef _Float16 f16x8 __attribute__((ext_vector_type(8)));
typedef float f32x4 __attribute__((ext_vector_type(4)));

#define HW 65536
#define W_ 256
#define H_ 256
#define C_ 64

__device__ __forceinline__ ushort f2hu(float f) { union { ushort u; _Float16 h; } x; x.h = (_Float16)f; return x.u; }
__device__ __forceinline__ float hu2f(ushort u) { union { ushort u; _Float16 h; } x; x.u = u; return (float)x.h; }
__device__ __forceinline__ h2 u2h2(uint u) { union { uint u; h2 h; } x; x.u = u; return x.h; }
__device__ __forceinline__ uint h22u(h2 h) { union { uint u; h2 h; } x; x.h = h; return x.u; }

#define MFMA16(a, b, c) __builtin_amdgcn_mfma_f32_16x16x32_f16((a), (b), (c), 0, 0, 0)

// ---------------- convert 6 weight matrices (4096 fp32 each) to f16, same [o][c] layout ----------------
__global__ __launch_bounds__(256) void wconv_k(const float* __restrict__ a0, const float* __restrict__ a1,
                                               const float* __restrict__ a2, const float* __restrict__ a3,
                                               const float* __restrict__ a4, const float* __restrict__ a5,
                                               ushort* __restrict__ dst) {
    int m = blockIdx.x;
    const float* src = m == 0 ? a0 : m == 1 ? a1 : m == 2 ? a2 : m == 3 ? a3 : m == 4 ? a4 : a5;
    ushort* d = dst + m * 4096;
    for (int i = threadIdx.x; i < 4096; i += 256) d[i] = f2hu(src[i]);
}

// ---------------- pack pa_w (6272 f32) + four dw weight sets (576 f32 each) into duplicated-h2 ----------------
__global__ __launch_bounds__(256) void wpk2_k(const float* __restrict__ pa,
                                              const float* __restrict__ d0, const float* __restrict__ d1,
                                              const float* __restrict__ d2, const float* __restrict__ d3,
                                              uint* __restrict__ dst) {
    int i = blockIdx.x * 256 + threadIdx.x;
    float v;
    if (i < 6272) v = pa[i];
    else if (i < 6848) v = d0[i - 6272];
    else if (i < 7424) v = d1[i - 6848];
    else if (i < 8000) v = d2[i - 7424];
    else if (i < 8576) v = d3[i - 8000];
    else return;
    ushort hv = f2hu(v);
    dst[i] = (uint)hv | ((uint)hv << 16);
}

// ---------------- transpose NCHW f32 -> channels-last f16 [pix][c] ----------------
__global__ __launch_bounds__(256) void xt_k(const float* __restrict__ xl, const float* __restrict__ xr,
                                            ushort* __restrict__ dl, ushort* __restrict__ dr) {
    __shared__ __align__(16) ushort t[64 * 72];   // [pix][c], stride 72 (rows 16B-aligned)
    const float* x = blockIdx.y ? xr : xl;
    ushort* d = blockIdx.y ? dr : dl;
    int pix0 = blockIdx.x * 64;
    int b = pix0 >> 16, hw0 = pix0 & 65535;
    const float* xb = x + ((size_t)b << 22) + hw0;
    int tid = threadIdx.x;
    int pl = tid & 63, cg = tid >> 6;
#pragma unroll
    for (int i = 0; i < 16; ++i) {
        int c = cg * 16 + i;
        t[pl * 72 + c] = f2hu(xb[((size_t)c << 16) + pl]);
    }
    __syncthreads();
    uint4* dst = (uint4*)(d + (size_t)pix0 * 64);
#pragma unroll
    for (int u = 0; u < 2; ++u) {
        int idx = u * 256 + tid;        // 512 uint4 per block
        int p = idx >> 3;               // pixel
        int c0 = (idx & 7) * 8;
        dst[idx] = *(const uint4*)&t[p * 72 + c0];
    }
}

// ---------------- conv1x1 via MFMA: channels-last f16 in, f16 NCHW out ----------------
__global__ __launch_bounds__(256, 2) void c1_k(const ushort* __restrict__ xt,
                                               const ushort* __restrict__ wf,
                                               const float* __restrict__ bias,
                                               ushort* __restrict__ y) {
    __shared__ ushort sY[64 * 264];     // [o][pix], stride 264
    int tid = threadIdx.x;
    int wv = tid >> 6, lane = tid & 63;
    int l15 = lane & 15, quad = lane >> 4;
    int pix0 = blockIdx.x * 256;
    int b = pix0 >> 16, hw0 = pix0 & 65535;

    f16x8 aX[4][2];
#pragma unroll
    for (int mt = 0; mt < 4; ++mt) {
        int pixg = pix0 + wv * 64 + mt * 16 + l15;
#pragma unroll
        for (int kc = 0; kc < 2; ++kc)
            aX[mt][kc] = *(const f16x8*)(xt + (size_t)pixg * 64 + kc * 32 + quad * 8);
    }
    f16x8 bW[4][2];
#pragma unroll
    for (int nt = 0; nt < 4; ++nt)
#pragma unroll
        for (int kc = 0; kc < 2; ++kc)
            bW[nt][kc] = *(const f16x8*)(wf + (nt * 16 + l15) * 64 + kc * 32 + quad * 8);

    f32x4 acc[4][4];
#pragma unroll
    for (int mt = 0; mt < 4; ++mt)
#pragma unroll
        for (int nt = 0; nt < 4; ++nt) {
            f32x4 s = (f32x4)(0.0f);
            s = MFMA16(aX[mt][0], bW[nt][0], s);
            s = MFMA16(aX[mt][1], bW[nt][1], s);
            acc[mt][nt] = s;
        }

#pragma unroll
    for (int nt = 0; nt < 4; ++nt) {
        int o = nt * 16 + l15;
        float bv = bias[o];
#pragma unroll
        for (int mt = 0; mt < 4; ++mt) {
            int pixl = wv * 64 + mt * 16 + quad * 4;
#pragma unroll
            for (int r = 0; r < 4; r += 2) {
                h2 hh;
                hh.x = (_Float16)(acc[mt][nt][r] + bv);
                hh.y = (_Float16)(acc[mt][nt][r + 1] + bv);
                *(h2*)&sY[o * 264 + pixl + r] = hh;
            }
        }
    }
    __syncthreads();
    ushort* yb = y + ((size_t)b << 22) + hw0;
#pragma unroll
    for (int i = 0; i < 16; ++i) {
        int o = wv * 16 + i;
        uint2 v = *(const uint2*)&sY[o * 264 + lane * 4];
        *(uint2*)(yb + ((size_t)o << 16) + lane * 4) = v;
    }
}

// ------- depthwise 3x3 (zero pad) + bias, NCHW f16 in -> f16 out; h2-packed -------
// lane owns column pair (wbase, wbase+1); 9 aligned u32 loads per channel.
// mode==0: out[bh*16384 + w*64 + c]   (channels-last, for Q)
// mode==2: out[bh*16384 + c*256 + w]  (plane layout, for V)
__global__ __launch_bounds__(256) void dw3x3_t_k(const ushort* __restrict__ x,
                                                 const uint* __restrict__ wd,   // [c][9] duplicated h2
                                                 const float* __restrict__ bias,
                                                 ushort* __restrict__ out,
                                                 int mode) {
    int wt = blockIdx.x;   // 0..3 (w tile of 64)
    int h  = blockIdx.y;   // 0..255
    int b  = blockIdx.z;   // 0..1
    int tid = threadIdx.x;
    int wp = tid & 31;          // pair index
    int cg = tid >> 5;          // 0..7
    int w0 = wt * 64;
    int wbase = w0 + 2 * wp;
    __shared__ uint tile2[64 * 33];   // [c][wpair] packed h2

    bool hok[3]; int hv3[3];
#pragma unroll
    for (int dy = 0; dy < 3; ++dy) {
        int hh = h + dy - 1;
        hok[dy] = (hh >= 0 && hh < H_);
        hv3[dy] = hh < 0 ? 0 : (hh > 255 ? 255 : hh);
    }
    bool pok = (wbase != 0);
    bool nok = (wbase + 2 < 256);

#pragma unroll
    for (int i = 0; i < 8; ++i) {
        int c = cg * 8 + i;
        const uint* wc = wd + c * 9;
        float bv = bias[c];
        h2 acc; acc.x = (_Float16)bv; acc.y = (_Float16)bv;
        const ushort* xp = x + (((size_t)b * 64 + c) << 16);
#pragma unroll
        for (int dy = 0; dy < 3; ++dy) {
            if (!hok[dy]) continue;                 // block-uniform branch
            const ushort* row = xp + hv3[dy] * W_;
            uint cur = *(const uint*)(row + wbase);
            uint prv = pok ? *(const uint*)(row + wbase - 2) : 0u;
            uint nxt = nok ? *(const uint*)(row + wbase + 2) : 0u;
            uint m1 = (cur << 16) | (prv >> 16);    // (x[w-1], x[w])
            uint p1 = (nxt << 16) | (cur >> 16);    // (x[w+1], x[w+2])
            acc += u2h2(wc[dy * 3 + 0]) * u2h2(m1);
            acc += u2h2(wc[dy * 3 + 1]) * u2h2(cur);
            acc += u2h2(wc[dy * 3 + 2]) * u2h2(p1);
        }
        tile2[c * 33 + wp] = h22u(acc);
    }
    __syncthreads();

    const ushort* tv = (const ushort*)tile2;        // element (c, wl) = tv[c*66 + wl]
    size_t bh16 = ((size_t)b * H_ + h) * (size_t)(W_ * 64);
    if (mode == 0) {
        uint4* og = (uint4*)(out + bh16 + (size_t)w0 * 64);
#pragma unroll
        for (int u = 0; u < 2; ++u) {
            int i0 = (u * 256 + tid) * 8;
            ushort vals[8];
#pragma unroll
            for (int k = 0; k < 8; ++k) {
                int i = i0 + k;                      // w = i>>6, c = i&63
                vals[k] = tv[(i & 63) * 66 + (i >> 6)];
            }
            uint4 o;
            o.x = (uint)vals[0] | ((uint)vals[1] << 16);
            o.y = (uint)vals[2] | ((uint)vals[3] << 16);
            o.z = (uint)vals[4] | ((uint)vals[5] << 16);
            o.w = (uint)vals[6] | ((uint)vals[7] << 16);
            og[u * 256 + tid] = o;
        }
    } else {
#pragma unroll
        for (int u = 0; u < 2; ++u) {
            int i = u * 256 + tid;                   // uint4 index
            int c = i >> 3, wch = i & 7;
            ushort vals[8];
#pragma unroll
            for (int k = 0; k < 8; ++k) vals[k] = tv[c * 66 + wch * 8 + k];
            uint4 o;
            o.x = (uint)vals[0] | ((uint)vals[1] << 16);
            o.y = (uint)vals[2] | ((uint)vals[3] << 16);
            o.z = (uint)vals[4] | ((uint)vals[5] << 16);
            o.w = (uint)vals[6] | ((uint)vals[7] << 16);
            *(uint4*)(out + bh16 + (size_t)c * 256 + w0 + wch * 8) = o;
        }
    }
}

// ---------------- combined MFMA attention (unchanged, verified) ----------------
__global__ __launch_bounds__(256, 2) void att2_k(const ushort* __restrict__ Ql,
                                                 const ushort* __restrict__ Qr,
                                                 const ushort* __restrict__ Vl,
                                                 const ushort* __restrict__ Vr,
                                                 ushort* __restrict__ Fr2l,
                                                 ushort* __restrict__ Fl2r) {
    int bh = blockIdx.x;
    int tid = threadIdx.x;
    int wv = tid >> 6, lane = tid & 63;
    int l15 = lane & 15, quad = lane >> 4;
    __shared__ ushort sE[256 * 72];    // E row-major [p][kcol], stride 72
    __shared__ ushort sEt[64 * 264];   // E col-major [kcol][p], stride 264

    const ushort* qlb = Ql + (size_t)bh * 16384;
    const ushort* qrb = Qr + (size_t)bh * 16384;
    const ushort* vlb = Vl + (size_t)bh * 16384;
    const ushort* vrb = Vr + (size_t)bh * 16384;
    int p0 = wv * 64;
    int c0 = wv * 16;

    f16x8 aQ[4][2];
#pragma unroll
    for (int mt = 0; mt < 4; ++mt)
#pragma unroll
        for (int kc = 0; kc < 2; ++kc)
            aQ[mt][kc] = *(const f16x8*)(qlb + (p0 + mt * 16 + l15) * 64 + kc * 32 + quad * 8);

    f16x8 onesf;
#pragma unroll
    for (int i = 0; i < 8; ++i) onesf[i] = (_Float16)1.0f;

    f32x4 num1[4][4];
    f32x4 den[4];
#pragma unroll
    for (int mt = 0; mt < 4; ++mt) {
        den[mt] = (f32x4)(0.0f);
#pragma unroll
        for (int nt = 0; nt < 4; ++nt) num1[mt][nt] = (f32x4)(0.0f);
    }

    for (int kt = 0; kt < 4; ++kt) {
        int k0 = kt * 64;
        f32x4 S[4][4];
#pragma unroll
        for (int nt = 0; nt < 4; ++nt) {
            f16x8 bQ[2];
#pragma unroll
            for (int kc = 0; kc < 2; ++kc)
                bQ[kc] = *(const f16x8*)(qrb + (k0 + nt * 16 + l15) * 64 + kc * 32 + quad * 8);
#pragma unroll
            for (int mt = 0; mt < 4; ++mt) {
                f32x4 s = (f32x4)(0.0f);
                s = MFMA16(aQ[mt][0], bQ[0], s);
                s = MFMA16(aQ[mt][1], bQ[1], s);
                S[mt][nt] = s;
            }
        }
#pragma unroll
        for (int mt = 0; mt < 4; ++mt)
#pragma unroll
            for (int nt = 0; nt < 4; ++nt)
#pragma unroll
                for (int r = 0; r < 4; ++r)
                    S[mt][nt][r] = __expf(S[mt][nt][r] * 0.125f);

        __syncthreads();
#pragma unroll
        for (int mt = 0; mt < 4; ++mt)
#pragma unroll
            for (int nt = 0; nt < 4; ++nt)
#pragma unroll
                for (int r = 0; r < 4; ++r)
                    sE[(p0 + mt * 16 + quad * 4 + r) * 72 + nt * 16 + l15] = f2hu(S[mt][nt][r]);
#pragma unroll
        for (int mt = 0; mt < 4; ++mt)
#pragma unroll
            for (int nt = 0; nt < 4; ++nt)
#pragma unroll
            for (int pr = 0; pr < 4; pr += 2) {
                h2 hh;
                hh.x = (_Float16)S[mt][nt][pr];
                hh.y = (_Float16)S[mt][nt][pr + 1];
                *(h2*)&sEt[(nt * 16 + l15) * 264 + p0 + mt * 16 + quad * 4 + pr] = hh;
            }
        __syncthreads();

        f16x8 aE[4][2];
#pragma unroll
        for (int mt = 0; mt < 4; ++mt)
#pragma unroll
            for (int kc = 0; kc < 2; ++kc)
                aE[mt][kc] = *(const f16x8*)&sE[(p0 + mt * 16 + l15) * 72 + kc * 32 + quad * 8];
#pragma unroll
        for (int mt = 0; mt < 4; ++mt) {
            den[mt] = MFMA16(aE[mt][0], onesf, den[mt]);
            den[mt] = MFMA16(aE[mt][1], onesf, den[mt]);
        }
#pragma unroll
        for (int nt = 0; nt < 4; ++nt) {
            f16x8 bV[2];
#pragma unroll
            for (int kc = 0; kc < 2; ++kc)
                bV[kc] = *(const f16x8*)(vrb + (nt * 16 + l15) * 256 + k0 + kc * 32 + quad * 8);
#pragma unroll
            for (int mt = 0; mt < 4; ++mt) {
                num1[mt][nt] = MFMA16(aE[mt][0], bV[0], num1[mt][nt]);
                num1[mt][nt] = MFMA16(aE[mt][1], bV[1], num1[mt][nt]);
            }
        }
        f32x4 num2[4], den2[4];
#pragma unroll
        for (int mt = 0; mt < 4; ++mt) { num2[mt] = (f32x4)(0.0f); den2[mt] = (f32x4)(0.0f); }
        for (int pc = 0; pc < 8; ++pc) {
            f16x8 bL = *(const f16x8*)(vlb + (c0 + l15) * 256 + pc * 32 + quad * 8);
#pragma unroll
            for (int mt = 0; mt < 4; ++mt) {
                f16x8 aT = *(const f16x8*)&sEt[(mt * 16 + l15) * 264 + pc * 32 + quad * 8];
                num2[mt] = MFMA16(aT, bL, num2[mt]);
                den2[mt] = MFMA16(aT, onesf, den2[mt]);
            }
        }
#pragma unroll
        for (int mt = 0; mt < 4; ++mt)
#pragma unroll
            for (int r = 0; r < 4; ++r) {
                float v = num2[mt][r] * (1.0f / den2[mt][r]);
                Fl2r[(size_t)bh * 16384 + (k0 + mt * 16 + quad * 4 + r) * 64 + c0 + l15] = f2hu(v);
            }
    }
#pragma unroll
    for (int mt = 0; mt < 4; ++mt)
#pragma unroll
        for (int r = 0; r < 4; ++r) {
            float inv = 1.0f / den[mt][r];
#pragma unroll
            for (int nt = 0; nt < 4; ++nt) {
                float v = num1[mt][nt][r] * inv;
                Fr2l[(size_t)bh * 16384 + (p0 + mt * 16 + quad * 4 + r) * 64 + nt * 16 + l15] = f2hu(v);
            }
        }
}

// ------- pattn1 = lp3(F_r2l) + rp3(F_l2r) via MFMA; channels-last f16 in, NCHW f16 out -------
__global__ __launch_bounds__(256, 2) void p3m_k(const ushort* __restrict__ F1,
                                                const ushort* __restrict__ F2,
                                                const ushort* __restrict__ wf1,
                                                const float* __restrict__ b1,
                                                const ushort* __restrict__ wf2,
                                                const float* __restrict__ b2,
                                                ushort* __restrict__ outp) {
    __shared__ ushort sY[64 * 264];
    int tid = threadIdx.x;
    int wv = tid >> 6, lane = tid & 63;
    int l15 = lane & 15, quad = lane >> 4;
    int pix0 = blockIdx.x * 256;
    int b = pix0 >> 16, hw0 = pix0 & 65535;

    f32x4 acc[4][4];
#pragma unroll
    for (int mt = 0; mt < 4; ++mt)
#pragma unroll
        for (int nt = 0; nt < 4; ++nt) acc[mt][nt] = (f32x4)(0.0f);

    for (int mat = 0; mat < 2; ++mat) {
        const ushort* F = mat == 0 ? F1 : F2;
        const ushort* wf = mat == 0 ? wf1 : wf2;
        f16x8 aF[4][2], bW[4][2];
#pragma unroll
        for (int mt = 0; mt < 4; ++mt) {
            int pixg = pix0 + wv * 64 + mt * 16 + l15;
#pragma unroll
            for (int kc = 0; kc < 2; ++kc)
                aF[mt][kc] = *(const f16x8*)(F + (size_t)pixg * 64 + kc * 32 + quad * 8);
        }
#pragma unroll
        for (int nt = 0; nt < 4; ++nt)
#pragma unroll
            for (int kc = 0; kc < 2; ++kc)
                bW[nt][kc] = *(const f16x8*)(wf + (nt * 16 + l15) * 64 + kc * 32 + quad * 8);
#pragma unroll
        for (int mt = 0; mt < 4; ++mt)
#pragma unroll
            for (int nt = 0; nt < 4; ++nt) {
                acc[mt][nt] = MFMA16(aF[mt][0], bW[nt][0], acc[mt][nt]);
                acc[mt][nt] = MFMA16(aF[mt][1], bW[nt][1], acc[mt][nt]);
            }
    }

#pragma unroll
    for (int nt = 0; nt < 4; ++nt) {
        int o = nt * 16 + l15;
        float bv = b1[o] + b2[o];
#pragma unroll
        for (int mt = 0; mt < 4; ++mt) {
            int pixl = wv * 64 + mt * 16 + quad * 4;
#pragma unroll
            for (int r = 0; r < 4; r += 2) {
                h2 hh;
                hh.x = (_Float16)(acc[mt][nt][r] + bv);
                hh.y = (_Float16)(acc[mt][nt][r + 1] + bv);
                *(h2*)&sY[o * 264 + pixl + r] = hh;
            }
        }
    }
    __syncthreads();
    ushort* yb = outp + ((size_t)b << 22) + hw0;
#pragma unroll
    for (int i = 0; i < 16; ++i) {
        int o = wv * 16 + i;
        uint2 v = *(const uint2*)&sY[o * 264 + lane * 4];
        *(uint2*)(yb + ((size_t)o << 16) + lane * 4) = v;
    }
}

// ------- pixel attention 7x7 reflect + double sigmoid + blend; packed-h2, LDS-tiled -------
// block = 128 threads, one (b,c,16-row) tile; lane owns output cols (w, w+128) packed in h2.
// LDS 23.9 KB -> 6 blocks/CU; epilogue reloads x_l/x_r (L2-hot).
__global__ __launch_bounds__(128) void p4pk_k(const float* __restrict__ x_l,
                                              const float* __restrict__ x_r,
                                              const ushort* __restrict__ pt,
                                              const uint* __restrict__ pw2,
                                              const float* __restrict__ pb,
                                              float* __restrict__ out) {
    __shared__ uint s2a[22 * 136];
    __shared__ uint p2a[22 * 136];
    int tid = threadIdx.x;           // 0..127
    int tile = blockIdx.x & 15;
    int bc = blockIdx.x >> 4;        // b*64 + c
    int c = bc & 63;
    int h0 = tile << 4;
    size_t cbase = (size_t)bc << 16;

#pragma unroll
    for (int r = 0; r < 22; ++r) {
        int hh = h0 + r - 3;
        hh = hh < 0 ? -hh : (hh > 255 ? 510 - hh : hh);
        size_t rb = cbase + (size_t)hh * 256;
        int k1 = tid - 3;
        int s1 = k1 < 0 ? -k1 : k1;          // left reflect
        int k2 = tid + 125;                  // always <= 252, in range
        float a1 = x_l[rb + s1] + x_r[rb + s1];
        float a2 = x_l[rb + k2] + x_r[rb + k2];
        s2a[r * 136 + tid] = (uint)f2hu(a1) | ((uint)f2hu(a2) << 16);
        p2a[r * 136 + tid] = (uint)pt[rb + s1] | ((uint)pt[rb + k2] << 16);
        if (tid < 6) {                       // entries e = 128..133
            int e = 128 + tid;
            int k1b = e - 3;                 // 125..130, in range
            int k2b = e + 125;               // 253..258
            int s2b = k2b > 255 ? 510 - k2b : k2b;
            float b1v = x_l[rb + k1b] + x_r[rb + k1b];
            float b2v = x_l[rb + s2b] + x_r[rb + s2b];
            s2a[r * 136 + e] = (uint)f2hu(b1v) | ((uint)f2hu(b2v) << 16);
            p2a[r * 136 + e] = (uint)pt[rb + k1b] | ((uint)pt[rb + s2b] << 16);
        }
    }
    __syncthreads();

    const uint* wA = pw2 + c * 98;       // duplicated-h2 weights vs s
    const uint* wB = wA + 49;            // vs pattn1
    float bv = pb[c];
    h2 bias2; bias2.x = (_Float16)bv; bias2.y = (_Float16)bv;
    h2 a0 = bias2, a1 = bias2, a2 = bias2, a3 = bias2, a4 = bias2, a5 = bias2, a6 = bias2;

#pragma unroll
    for (int r = 0; r < 22; ++r) {
#pragma unroll
        for (int j = 0; j < 7; ++j) {
            h2 sv = u2h2(s2a[r * 136 + tid + j]);
            h2 pv = u2h2(p2a[r * 136 + tid + j]);
            a0 += u2h2(wA[42 + j]) * sv + u2h2(wB[42 + j]) * pv;
            a1 += u2h2(wA[35 + j]) * sv + u2h2(wB[35 + j]) * pv;
            a2 += u2h2(wA[28 + j]) * sv + u2h2(wB[28 + j]) * pv;
            a3 += u2h2(wA[21 + j]) * sv + u2h2(wB[21 + j]) * pv;
            a4 += u2h2(wA[14 + j]) * sv + u2h2(wB[14 + j]) * pv;
            a5 += u2h2(wA[ 7 + j]) * sv + u2h2(wB[ 7 + j]) * pv;
            a6 += u2h2(wA[     j]) * sv + u2h2(wB[     j]) * pv;
        }
        if (r >= 6) {
            int o = r - 6;
            size_t idx = cbase + (size_t)(h0 + o) * 256 + tid;
            float xlx = x_l[idx], xly = x_l[idx + 128];
            float xrx = x_r[idx], xry = x_r[idx + 128];
            float accx = (float)a0.x, accy = (float)a0.y;
            float s1x = 1.0f / (1.0f + __expf(-accx));
            float s1y = 1.0f / (1.0f + __expf(-accy));
            float ax = 1.0f / (1.0f + __expf(-s1x));
            float ay = 1.0f / (1.0f + __expf(-s1y));
            out[idx] = xrx + ax * (xlx - xrx);
            out[idx + 128] = xry + ay * (xly - xry);
        }
        a0 = a1; a1 = a2; a2 = a3; a3 = a4; a4 = a5; a5 = a6; a6 = bias2;
    }
}

extern "C" void kernel_launch(void* const* d_in, const int* in_sizes, int n_in,
                              void* d_out, int out_size, void* d_ws, size_t ws_size,
                              hipStream_t stream) {
    const float* x_l = (const float*)d_in[0];
    const float* x_r = (const float*)d_in[1];
    const float* lp1_w1 = (const float*)d_in[2];
    const float* lp1_b1 = (const float*)d_in[3];
    const float* lp1_w2 = (const float*)d_in[4];
    const float* lp1_b2 = (const float*)d_in[5];
    const float* rp1_w1 = (const float*)d_in[6];
    const float* rp1_b1 = (const float*)d_in[7];
    const float* rp1_w2 = (const float*)d_in[8];
    const float* rp1_b2 = (const float*)d_in[9];
    const float* lp2_w1 = (const float*)d_in[10];
    const float* lp2_b1 = (const float*)d_in[11];
    const float* lp2_w2 = (const float*)d_in[12];
    const float* lp2_b2 = (const float*)d_in[13];
    const float* rp2_w1 = (const float*)d_in[14];
    const float* rp2_b1 = (const float*)d_in[15];
    const float* rp2_w2 = (const float*)d_in[16];
    const float* rp2_b2 = (const float*)d_in[17];
    const float* lp3_w = (const float*)d_in[18];
    const float* lp3_b = (const float*)d_in[19];
    const float* rp3_w = (const float*)d_in[20];
    const float* rp3_b = (const float*)d_in[21];
    const float* pa_w = (const float*)d_in[22];
    const float* pa_b = (const float*)d_in[23];

    const size_t N = (size_t)2 * 64 * 256 * 256;    // 8388608
    char* ws = (char*)d_ws;
    ushort* tmp  = (ushort*)ws;                     // N u16 (conv1x1 out, later pattn1)
    ushort* wf16 = (ushort*)(ws + N * 2);           // 6 * 4096 f16 weights [o][c]
    uint*   wp2  = (uint*)(ws + N * 2 + 65536);     // 8576 packed-h2 weights (pa + 4 dw sets)
    ushort* q_l   = (ushort*)(ws + N * 4);
    ushort* q_r   = q_l + N;
    ushort* v_l   = q_r + N;                        // plane layout
    ushort* v_r   = v_l + N;                        // plane layout
    ushort* f_r2l = v_r + N;
    ushort* f_l2r = f_r2l + N;
    // xlt/xrt alias f_r2l/f_l2r (dead until att2 writes them)
    ushort* xlt = f_r2l;
    ushort* xrt = f_l2r;

    const uint* wdw = wp2 + 6272;                   // 4 * 576 dw weights

    dim3 blk(256);
    dim3 g_xt(2048, 2);        // pix-tiles of 64, {l,r}
    dim3 g_c1(512);            // B*HW/256
    dim3 g_dw(4, 256, 2);      // wtile, h, b
    dim3 g_att(512);           // b*h
    dim3 g_p3(512);            // B*HW/256
    dim3 g_p4(2048);           // (b*64+c)*16 + htile

    wconv_k<<<6, blk, 0, stream>>>(lp1_w1, rp1_w1, lp2_w1, rp2_w1, lp3_w, rp3_w, wf16);
    wpk2_k<<<34, blk, 0, stream>>>(pa_w, lp1_w2, rp1_w2, lp2_w2, rp2_w2, wp2);
    xt_k<<<g_xt, blk, 0, stream>>>(x_l, x_r, xlt, xrt);

    c1_k<<<g_c1, blk, 0, stream>>>(xlt, wf16 + 0 * 4096, lp1_b1, tmp);
    dw3x3_t_k<<<g_dw, blk, 0, stream>>>(tmp, wdw + 0 * 576, lp1_b2, q_l, 0);
    c1_k<<<g_c1, blk, 0, stream>>>(xrt, wf16 + 1 * 4096, rp1_b1, tmp);
    dw3x3_t_k<<<g_dw, blk, 0, stream>>>(tmp, wdw + 1 * 576, rp1_b2, q_r, 0);
    c1_k<<<g_c1, blk, 0, stream>>>(xlt, wf16 + 2 * 4096, lp2_b1, tmp);
    dw3x3_t_k<<<g_dw, blk, 0, stream>>>(tmp, wdw + 2 * 576, lp2_b2, v_l, 2);
    c1_k<<<g_c1, blk, 0, stream>>>(xrt, wf16 + 3 * 4096, rp2_b1, tmp);
    dw3x3_t_k<<<g_dw, blk, 0, stream>>>(tmp, wdw + 3 * 576, rp2_b2, v_r, 2);

    att2_k<<<g_att, blk, 0, stream>>>(q_l, q_r, v_l, v_r, f_r2l, f_l2r);

    p3m_k<<<g_p3, blk, 0, stream>>>(f_r2l, f_l2r, wf16 + 4 * 4096, lp3_b, wf16 + 5 * 4096, rp3_b, tmp);

    p4pk_k<<<g_p4, dim3(128), 0, stream>>>(x_l, x_r, tmp, wp2, pa_b, (float*)d_out);
}